// Round 1
// baseline (33.268 us; speedup 1.0000x reference)
//
#include <hip/hip_runtime.h>

// LIF layer scan: x (B=32,G=4,T=512,C=256) f32, per-channel w_input/w_leak.
// N = B*G = 128 independent sequences, C channels each -> 32768 chains.
// Each thread owns one (n,c) chain and scans t sequentially with a 32-deep
// register prefetch ring (x loads are state-independent).

constexpr int T_STEPS = 512;
constexpr int CCH     = 256;
constexpr int NSEQ    = 128;   // B*G
constexpr int D       = 32;    // prefetch depth (T_STEPS % D == 0)

__global__ __launch_bounds__(64, 1) void lif_kernel(
    const float* __restrict__ x,
    const float* __restrict__ w_input,
    const float* __restrict__ w_leak,
    float* __restrict__ out)
{
#pragma clang fp contract(off)
    const int tid = blockIdx.x * 64 + threadIdx.x;
    const int c = tid & (CCH - 1);
    const int n = tid >> 8;   // tid / CCH

    const float w = w_input[c];
    const float a = 1.0f - w_leak[c];

    const float* __restrict__ xp = x   + (size_t)n * T_STEPS * CCH + c;
    float*       __restrict__ op = out + (size_t)n * T_STEPS * CCH + c;

    // Prime the prefetch ring: x[0..D-1]
    float buf[D];
#pragma unroll
    for (int d = 0; d < D; ++d) buf[d] = xp[(size_t)d * CCH];

    float Vm = 0.0f, R = 0.0f;

    // Main loop: consume buf[k] (loaded D steps ago), refill with x[t+D].
    // Full unroll of the inner loop keeps buf[] statically indexed (registers).
    for (int t0 = 0; t0 < T_STEPS - D; t0 += D) {
#pragma unroll
        for (int k = 0; k < D; ++k) {
            const float xt = buf[k];
            buf[k] = xp[(size_t)(t0 + D + k) * CCH];

            // R = heaviside(Vm - 1)*1 + heaviside(R - 1)*(R - 1)   (old Vm, old R)
            const float spike = (Vm - 1.0f >= 0.0f) ? 1.0f : 0.0f;
            const float rdec  = (R  - 1.0f >= 0.0f) ? (R - 1.0f) : 0.0f;
            R = spike + rdec;

            // Vm = (w*xt + (1-wl)*Vm) * heaviside(-R)   (new R)
            // exact numpy op order: mul, mul, add — no FMA contraction
            const float v = (w * xt) + (a * Vm);
            Vm = (-R >= 0.0f) ? v : 0.0f;

            op[(size_t)(t0 + k) * CCH] = Vm;
        }
    }

    // Tail: last D steps, ring already holds x[T-D .. T-1]
#pragma unroll
    for (int k = 0; k < D; ++k) {
        const float xt = buf[k];
        const float spike = (Vm - 1.0f >= 0.0f) ? 1.0f : 0.0f;
        const float rdec  = (R  - 1.0f >= 0.0f) ? (R - 1.0f) : 0.0f;
        R = spike + rdec;
        const float v = (w * xt) + (a * Vm);
        Vm = (-R >= 0.0f) ? v : 0.0f;
        op[(size_t)(T_STEPS - D + k) * CCH] = Vm;
    }
}

extern "C" void kernel_launch(void* const* d_in, const int* in_sizes, int n_in,
                              void* d_out, int out_size, void* d_ws, size_t ws_size,
                              hipStream_t stream) {
    const float* x       = (const float*)d_in[0];
    const float* w_input = (const float*)d_in[1];
    const float* w_leak  = (const float*)d_in[2];
    float* out = (float*)d_out;

    dim3 grid((NSEQ * CCH) / 64);
    dim3 block(64);
    hipLaunchKernelGGL(lif_kernel, grid, block, 0, stream,
                       x, w_input, w_leak, out);
}